// Round 1
// 10384.366 us; speedup vs baseline: 1.0614x; 1.0614x over previous
//
#include <hip/hip_runtime.h>
#include <hip/hip_cooperative_groups.h>
#include <cstdint>
#include <cstddef>

namespace cg = cooperative_groups;

typedef __attribute__((ext_vector_type(8))) short short8;
typedef __attribute__((ext_vector_type(4))) short short4v;
typedef __attribute__((ext_vector_type(4))) float float4v;

#define T_STEPS 512
#define BATCH   64
#define IN_DIM  512
#define HID     1024
#define BH      (BATCH * HID)              /* 65536 */
#define OPS_SZ  ((size_t)T_STEPS * BH)     /* 33554432 */
#define NX      ((size_t)T_STEPS * BATCH * IN_DIM) /* 16777216 */
#define NWG     256
#define NTHR    1024
#define BAR_BYTES 2048

__device__ __forceinline__ float bf2f(unsigned short b) {
    return __builtin_bit_cast(float, ((unsigned)b) << 16);
}
__device__ __forceinline__ short f2bf(float f) {
    unsigned u = __builtin_bit_cast(unsigned, f);
    unsigned r = (u + 0x7FFFu + ((u >> 16) & 1u)) >> 16;   // round-nearest-even
    return (short)(unsigned short)r;
}
__device__ __forceinline__ float sigmoidf_(float v) { return 1.0f / (1.0f + __expf(-v)); }

struct u64x2 { unsigned long long a, b; };

// Coherent (agent-scope, L1/L2-bypassing) 16 B load of a bf16x8 fragment.
__device__ __forceinline__ short8 cohload8(const short* p) {
    unsigned long long* q = (unsigned long long*)p;
    u64x2 t;
    t.a = __hip_atomic_load(q,     __ATOMIC_RELAXED, __HIP_MEMORY_SCOPE_AGENT);
    t.b = __hip_atomic_load(q + 1, __ATOMIC_RELAXED, __HIP_MEMORY_SCOPE_AGENT);
    return __builtin_bit_cast(short8, t);
}
__device__ __forceinline__ void cohstore_h(short* p, short v) {
    __hip_atomic_store((unsigned short*)p, (unsigned short)v,
                       __ATOMIC_RELAXED, __HIP_MEMORY_SCOPE_AGENT);
}
__device__ __forceinline__ unsigned short cohload_h(const short* p) {
    return __hip_atomic_load((unsigned short*)p, __ATOMIC_RELAXED, __HIP_MEMORY_SCOPE_AGENT);
}

// Pure-atomic grid barrier: NO L2 writeback / invalidate. All cross-WG data
// (h state) moves via agent-scope coherent ops, so only ordering is needed.
__device__ __forceinline__ void grid_bar(unsigned* bar, int wg, unsigned e)
{
    asm volatile("s_waitcnt vmcnt(0)" ::: "memory");  // h write-through stores acked
    unsigned* sub  = bar + (wg >> 5) * 32;            // 8 counters, 128 B apart
    unsigned* root = bar + 256;
    unsigned* go   = bar + 288;
    __atomic_signal_fence(__ATOMIC_SEQ_CST);
    if (__hip_atomic_fetch_add(sub, 1u, __ATOMIC_RELAXED, __HIP_MEMORY_SCOPE_AGENT) == e * 32u - 1u)
        if (__hip_atomic_fetch_add(root, 1u, __ATOMIC_RELAXED, __HIP_MEMORY_SCOPE_AGENT) == e * 8u - 1u)
            __hip_atomic_store(go, e, __ATOMIC_RELAXED, __HIP_MEMORY_SCOPE_AGENT);
    while (__hip_atomic_load(go, __ATOMIC_RELAXED, __HIP_MEMORY_SCOPE_AGENT) < e)
        __builtin_amdgcn_s_sleep(1);
    __atomic_signal_fence(__ATOMIC_SEQ_CST);          // no hoisting of h loads above spin
}

// Plain-load GEMM (read-only A: pre-converted x). C[MT*16 x 16] += A * W^T segment.
template <int NC, int MT>
__device__ __forceinline__ void gemm_seg(const short* __restrict__ A, int lda,
                                         const short* __restrict__ W, int ldw,
                                         int kbase, int mbase, int col, int kq, float4v* acc)
{
#pragma unroll
    for (int kc = 0; kc < NC; ++kc) {
        const int k = kbase + kc * 32 + kq * 8;
        const short8 b = *(const short8*)(W + col * ldw + k);
#pragma unroll
        for (int mt = 0; mt < MT; ++mt) {
            const short8 a = *(const short8*)(A + (size_t)(mbase + mt * 16 + col) * lda + k);
            acc[mt] = __builtin_amdgcn_mfma_f32_16x16x32_bf16(a, b, acc[mt], 0, 0, 0);
        }
    }
}

// fp32-A fallback (x not pre-converted).
template <int NC, int MT>
__device__ __forceinline__ void gemm_seg_f32(const float* __restrict__ A, int lda,
                                             const short* __restrict__ W, int ldw,
                                             int kbase, int mbase, int col, int kq, float4v* acc)
{
#pragma unroll
    for (int kc = 0; kc < NC; ++kc) {
        const int k = kbase + kc * 32 + kq * 8;
        const short8 b = *(const short8*)(W + col * ldw + k);
#pragma unroll
        for (int mt = 0; mt < MT; ++mt) {
            const float* ap = A + (size_t)(mbase + mt * 16 + col) * lda + k;
            const float4v a0 = *(const float4v*)ap;
            const float4v a1 = *(const float4v*)(ap + 4);
            short8 a;
            a[0] = f2bf(a0[0]); a[1] = f2bf(a0[1]); a[2] = f2bf(a0[2]); a[3] = f2bf(a0[3]);
            a[4] = f2bf(a1[0]); a[5] = f2bf(a1[1]); a[6] = f2bf(a1[2]); a[7] = f2bf(a1[3]);
            acc[mt] = __builtin_amdgcn_mfma_f32_16x16x32_bf16(a, b, acc[mt], 0, 0, 0);
        }
    }
}

// Coherent-A GEMM, single W.
template <int NC, int MT>
__device__ __forceinline__ void gemm_coh1(const short* A, int lda,
                                          const short* __restrict__ W, int ldw,
                                          int kbase, int mbase, int col, int kq, float4v* acc)
{
#pragma unroll
    for (int kc = 0; kc < NC; ++kc) {
        const int k = kbase + kc * 32 + kq * 8;
        const short8 b = *(const short8*)(W + col * ldw + k);
#pragma unroll
        for (int mt = 0; mt < MT; ++mt) {
            const short8 a = cohload8(A + (size_t)(mbase + mt * 16 + col) * lda + k);
            acc[mt] = __builtin_amdgcn_mfma_f32_16x16x32_bf16(a, b, acc[mt], 0, 0, 0);
        }
    }
}

// Coherent-A GEMM, FUSED two W (one A read feeds both accumulators).
template <int NC, int MT>
__device__ __forceinline__ void gemm_coh2(const short* A, int lda,
                                          const short* __restrict__ W0,
                                          const short* __restrict__ W1, int ldw,
                                          int kbase, int mbase, int col, int kq,
                                          float4v* acc0, float4v* acc1)
{
#pragma unroll
    for (int kc = 0; kc < NC; ++kc) {
        const int k = kbase + kc * 32 + kq * 8;
        const short8 b0 = *(const short8*)(W0 + col * ldw + k);
        const short8 b1 = *(const short8*)(W1 + col * ldw + k);
#pragma unroll
        for (int mt = 0; mt < MT; ++mt) {
            const short8 a = cohload8(A + (size_t)(mbase + mt * 16 + col) * lda + k);
            acc0[mt] = __builtin_amdgcn_mfma_f32_16x16x32_bf16(a, b0, acc0[mt], 0, 0, 0);
            acc1[mt] = __builtin_amdgcn_mfma_f32_16x16x32_bf16(a, b1, acc1[mt], 0, 0, 0);
        }
    }
}

// Fully fused steady-state step: two coherent A streams, three weights.
// Both A-streams' loads issue together per k-chunk -> max MLP.
template <int NC, int MT>
__device__ __forceinline__ void gemm_fused(const short* A0, const short* A1, int lda,
                                           const short* __restrict__ W0,
                                           const short* __restrict__ W1,
                                           const short* __restrict__ W2, int ldw,
                                           int kbase, int mbase, int col, int kq,
                                           float4v* acc0, float4v* acc1)
{
#pragma unroll
    for (int kc = 0; kc < NC; ++kc) {
        const int k = kbase + kc * 32 + kq * 8;
        short8 a0[MT], a1[MT];
#pragma unroll
        for (int mt = 0; mt < MT; ++mt) {
            a0[mt] = cohload8(A0 + (size_t)(mbase + mt * 16 + col) * lda + k);
            a1[mt] = cohload8(A1 + (size_t)(mbase + mt * 16 + col) * lda + k);
        }
        const short8 b0 = *(const short8*)(W0 + col * ldw + k);
        const short8 b1 = *(const short8*)(W1 + col * ldw + k);
        const short8 b2 = *(const short8*)(W2 + col * ldw + k);
#pragma unroll
        for (int mt = 0; mt < MT; ++mt) {
            acc0[mt] = __builtin_amdgcn_mfma_f32_16x16x32_bf16(a0[mt], b0, acc0[mt], 0, 0, 0);
            acc1[mt] = __builtin_amdgcn_mfma_f32_16x16x32_bf16(a0[mt], b1, acc1[mt], 0, 0, 0);
            acc1[mt] = __builtin_amdgcn_mfma_f32_16x16x32_bf16(a1[mt], b2, acc1[mt], 0, 0, 0);
        }
    }
}

__global__ void __launch_bounds__(NTHR, 1)
lstm_persistent(const float* __restrict__ xf,
                const float* __restrict__ Wi0, const float* __restrict__ Wh0,
                const float* __restrict__ bi0, const float* __restrict__ bh0,
                const float* __restrict__ Wi1, const float* __restrict__ Wh1,
                const float* __restrict__ bi1, const float* __restrict__ bh1,
                const float* __restrict__ h0in, const float* __restrict__ c0in,
                float* __restrict__ out,
                unsigned* __restrict__ bar,
                short* __restrict__ h0b,   // ws: [2][BH] bf16 L0 h dbuf (coherent)
                short* __restrict__ h1b,   // ws: [2][BH] bf16 L1 h dbuf (coherent)
                short* __restrict__ xbf,   // ws: [NX] bf16 x
                int use_pre)
{
    __shared__ short w0x[16][520];
    __shared__ short w0h[16][1032];
    __shared__ short w1x[16][1032];
    __shared__ short w1h[16][1032];
    __shared__ float gbuf[8][64][17];        // 8 K-partials
    __shared__ float bias0[16], bias1[16];
    __shared__ float cl0[64][4], cl1[64][4];

    const int wg   = blockIdx.x;
    const int tid  = threadIdx.x;
    const int wave = tid >> 6;
    const int lane = tid & 63;
    const int col  = lane & 15;
    const int kq   = lane >> 4;
    const int mq   = wave >> 3;          // 0..1  M-half (rows mq*32 .. +32)
    const int kk   = wave & 7;           // 0..7  K-eighth
    const int mb   = mq * 32;
    const int khb  = kk * 128;           // hh-GEMM K base (K=1024 / 8)
    const int kxb  = kk * 64;            // x-GEMM  K base (K=512  / 8)
    const int u0   = wg << 2;
    const int b    = tid >> 2;           // only valid for tid < 256
    const int uu   = tid & 3;
    const int ug   = u0 + uu;
    const size_t ci = (size_t)b * HID + ug;

#define GROW(cc) ((size_t)((cc) >> 2) * HID + u0 + ((cc) & 3))
    for (int idx = tid; idx < 16 * 128; idx += NTHR) {
        const int cc = idx >> 7, ch = (idx & 127) << 2;
        const float4v v = *(const float4v*)(Wi0 + GROW(cc) * IN_DIM + ch);
        short4v s; s[0] = f2bf(v[0]); s[1] = f2bf(v[1]); s[2] = f2bf(v[2]); s[3] = f2bf(v[3]);
        *(short4v*)&w0x[cc][ch] = s;
    }
    for (int idx = tid; idx < 16 * 256; idx += NTHR) {
        const int cc = idx >> 8, ch = (idx & 255) << 2;
        const size_t off = GROW(cc) * HID + ch;
        {
            const float4v v = *(const float4v*)(Wh0 + off);
            short4v s; s[0] = f2bf(v[0]); s[1] = f2bf(v[1]); s[2] = f2bf(v[2]); s[3] = f2bf(v[3]);
            *(short4v*)&w0h[cc][ch] = s;
        }
        {
            const float4v v = *(const float4v*)(Wi1 + off);
            short4v s; s[0] = f2bf(v[0]); s[1] = f2bf(v[1]); s[2] = f2bf(v[2]); s[3] = f2bf(v[3]);
            *(short4v*)&w1x[cc][ch] = s;
        }
        {
            const float4v v = *(const float4v*)(Wh1 + off);
            short4v s; s[0] = f2bf(v[0]); s[1] = f2bf(v[1]); s[2] = f2bf(v[2]); s[3] = f2bf(v[3]);
            *(short4v*)&w1h[cc][ch] = s;
        }
    }
    if (tid < 16) {
        bias0[tid] = bi0[GROW(tid)] + bh0[GROW(tid)];
        bias1[tid] = bi1[GROW(tid)] + bh1[GROW(tid)];
    }
    if (tid < 256) {
        cl0[b][uu] = c0in[ci];
        cl1[b][uu] = c0in[BH + ci];
        h0b[BH + ci] = f2bf(h0in[ci]);        // plain; CG sync below publishes
        h1b[BH + ci] = f2bf(h0in[BH + ci]);
    }

    if (wg == 0) {
        for (int i = tid; i < 320; i += NTHR)
            __hip_atomic_store(bar + i, 0u, __ATOMIC_RELAXED, __HIP_MEMORY_SCOPE_AGENT);
    }
    if (use_pre) {
        const size_t gtid = (size_t)blockIdx.x * NTHR + tid;
        for (size_t i = gtid * 4; i < NX; i += (size_t)NWG * NTHR * 4) {
            const float4v v = *(const float4v*)(xf + i);
            short4v s; s[0] = f2bf(v[0]); s[1] = f2bf(v[1]); s[2] = f2bf(v[2]); s[3] = f2bf(v[3]);
            *(short4v*)(xbf + i) = s;
        }
    }

    cg::grid_group grid = cg::this_grid();   // bootstrap: full release-acquire once
    __threadfence();
    grid.sync();

    const float4v z = {0.f, 0.f, 0.f, 0.f};

    // Super-step s: layer 0 computes t=s, layer 1 computes t=s-1.
    for (int s = 0; s <= T_STEPS; ++s) {
        float4v accL0[2] = {z, z};
        float4v accL1[2] = {z, z};

        // x-GEMM has no h dependency: run it BEFORE the barrier to overlap
        // barrier skew / store drain with useful MFMA work.
        if (s < T_STEPS) {
            if (use_pre)
                gemm_seg<2, 2>(xbf + (size_t)s * BATCH * IN_DIM, IN_DIM,
                               &w0x[0][0], 520, kxb, mb, col, kq, accL0);
            else
                gemm_seg_f32<2, 2>(xf + (size_t)s * BATCH * IN_DIM, IN_DIM,
                                   &w0x[0][0], 520, kxb, mb, col, kq, accL0);
        }

        if (s > 0) {
            __syncthreads();
            if (tid == 0) grid_bar(bar, wg, (unsigned)s);
            __syncthreads();
        }
        const short* h0p = h0b + (size_t)((s + 1) & 1) * BH;  // h0(s-1), also L1's input
        const short* h1p = h1b + (size_t)(s & 1) * BH;        // h1(s-2)

        if (s == 0) {
            gemm_coh2<4, 2>(h0p, HID, &w0h[0][0], &w1x[0][0], 1032,
                            khb, mb, col, kq, accL0, accL1);
        } else if (s < T_STEPS) {
            gemm_fused<4, 2>(h0p, h1p, HID, &w0h[0][0], &w1x[0][0], &w1h[0][0], 1032,
                             khb, mb, col, kq, accL0, accL1);
        } else {
            gemm_coh1<4, 2>(h0p, HID, &w1x[0][0], 1032, khb, mb, col, kq, accL1);
            gemm_coh1<4, 2>(h1p, HID, &w1h[0][0], 1032, khb, mb, col, kq, accL1);
        }

        if (s < T_STEPS) {  // ---- layer 0 reduce + elementwise ----
#pragma unroll
            for (int mt = 0; mt < 2; ++mt)
#pragma unroll
                for (int r = 0; r < 4; ++r)
                    gbuf[kk][mb + mt * 16 + kq * 4 + r][col] = accL0[mt][r];
            __syncthreads();
            if (tid < 256) {
                float g4[4];
#pragma unroll
                for (int gi_ = 0; gi_ < 4; ++gi_) {
                    float v = bias0[gi_ * 4 + uu];
#pragma unroll
                    for (int p = 0; p < 8; ++p) v += gbuf[p][b][gi_ * 4 + uu];
                    g4[gi_] = v;
                }
                const float cn = sigmoidf_(g4[1]) * cl0[b][uu] + sigmoidf_(g4[0]) * tanhf(g4[2]);
                const float hn = sigmoidf_(g4[3]) * tanhf(cn);
                cl0[b][uu] = cn;
                cohstore_h(h0b + (size_t)(s & 1) * BH + ci, f2bf(hn));
            }
            __syncthreads();  // gbuf reuse by layer 1
        }

        if (s >= 1) {  // ---- layer 1 reduce + elementwise (t = s-1) ----
            const int t = s - 1;
#pragma unroll
            for (int mt = 0; mt < 2; ++mt)
#pragma unroll
                for (int r = 0; r < 4; ++r)
                    gbuf[kk][mb + mt * 16 + kq * 4 + r][col] = accL1[mt][r];
            __syncthreads();
            if (tid < 256) {
                float g4[4];
#pragma unroll
                for (int gi_ = 0; gi_ < 4; ++gi_) {
                    float v = bias1[gi_ * 4 + uu];
#pragma unroll
                    for (int p = 0; p < 8; ++p) v += gbuf[p][b][gi_ * 4 + uu];
                    g4[gi_] = v;
                }
                const float cn = sigmoidf_(g4[1]) * cl1[b][uu] + sigmoidf_(g4[0]) * tanhf(g4[2]);
                const float hn = sigmoidf_(g4[3]) * tanhf(cn);
                cl1[b][uu] = cn;
                cohstore_h(h1b + (size_t)(t & 1) * BH + ci, f2bf(hn));
                out[(size_t)t * BH + ci] = hn;   // plain store, write-only stream
            }
            __syncthreads();
        }
    }

    if (tid < 256) {
        out[OPS_SZ + ci]                  = bf2f(cohload_h(h0b + (size_t)((T_STEPS - 1) & 1) * BH + ci));
        out[OPS_SZ + BH + ci]             = bf2f(cohload_h(h1b + (size_t)((T_STEPS - 1) & 1) * BH + ci));
        out[OPS_SZ + 2 * (size_t)BH + ci] = cl0[b][uu];
        out[OPS_SZ + 3 * (size_t)BH + ci] = cl1[b][uu];
    }
#undef GROW
}

extern "C" void kernel_launch(void* const* d_in, const int* in_sizes, int n_in,
                              void* d_out, int out_size, void* d_ws, size_t ws_size,
                              hipStream_t stream)
{
    const float* x    = (const float*)d_in[0];
    const float* h0   = (const float*)d_in[1];
    const float* c0   = (const float*)d_in[2];
    const float* Wi0  = (const float*)d_in[3];
    const float* Wh0  = (const float*)d_in[4];
    const float* bi0  = (const float*)d_in[5];
    const float* bh0  = (const float*)d_in[6];
    const float* Wi1  = (const float*)d_in[7];
    const float* Wh1  = (const float*)d_in[8];
    const float* bi1  = (const float*)d_in[9];
    const float* bh1  = (const float*)d_in[10];
    float* out = (float*)d_out;

    unsigned* bar = (unsigned*)d_ws;
    short* h0b = (short*)((char*)d_ws + BAR_BYTES);
    short* h1b = h0b + (size_t)2 * BH;
    short* xbf = h1b + (size_t)2 * BH;
    int use_pre = (ws_size >= BAR_BYTES + ((size_t)4 * BH + NX) * sizeof(short)) ? 1 : 0;

    void* args[] = {(void*)&x, (void*)&Wi0, (void*)&Wh0, (void*)&bi0, (void*)&bh0,
                    (void*)&Wi1, (void*)&Wh1, (void*)&bi1, (void*)&bh1,
                    (void*)&h0, (void*)&c0, (void*)&out,
                    (void*)&bar, (void*)&h0b, (void*)&h1b, (void*)&xbf, (void*)&use_pre};
    hipLaunchCooperativeKernel((void*)lstm_persistent, dim3(NWG), dim3(NTHR),
                               args, 0, stream);
}

// Round 2
// 7784.329 us; speedup vs baseline: 1.4159x; 1.3340x over previous
//
#include <hip/hip_runtime.h>
#include <hip/hip_cooperative_groups.h>
#include <cstdint>
#include <cstddef>

namespace cg = cooperative_groups;

typedef __attribute__((ext_vector_type(8))) short short8;
typedef __attribute__((ext_vector_type(4))) short short4v;
typedef __attribute__((ext_vector_type(4))) float float4v;

#define T_STEPS 512
#define BATCH   64
#define IN_DIM  512
#define HID     1024
#define BH      (BATCH * HID)              /* 65536 */
#define OPS_SZ  ((size_t)T_STEPS * BH)     /* 33554432 */
#define NX      ((size_t)T_STEPS * BATCH * IN_DIM) /* 16777216 */
#define NWG     256
#define NTHR    1024
#define BAR_BYTES 2048

__device__ __forceinline__ float bf2f(unsigned short b) {
    return __builtin_bit_cast(float, ((unsigned)b) << 16);
}
__device__ __forceinline__ short f2bf(float f) {
    unsigned u = __builtin_bit_cast(unsigned, f);
    unsigned r = (u + 0x7FFFu + ((u >> 16) & 1u)) >> 16;   // round-nearest-even
    return (short)(unsigned short)r;
}
__device__ __forceinline__ float sigmoidf_(float v) { return 1.0f / (1.0f + __expf(-v)); }

// h WRITE path stays agent-scope (bypasses L2, lands in L3 = coherence point).
__device__ __forceinline__ void cohstore_h(short* p, short v) {
    __hip_atomic_store((unsigned short*)p, (unsigned short)v,
                       __ATOMIC_RELAXED, __HIP_MEMORY_SCOPE_AGENT);
}
__device__ __forceinline__ unsigned short cohload_h(const short* p) {
    return __hip_atomic_load((unsigned short*)p, __ATOMIC_RELAXED, __HIP_MEMORY_SCOPE_AGENT);
}

// Pure-atomic grid barrier + ACQUIRE fence on exit.
// Producer side: agent-scope h stores are already in L3 when vmcnt(0) clears.
// Consumer side: buffer_inv (from the acquire fence) drops stale CLEAN L1/L2
// copies of the h parity buffer (read 2 steps ago), so the following PLAIN
// cached loads refill from L3 and subsequent CUs on the XCD hit L2.
__device__ __forceinline__ void grid_bar(unsigned* bar, int wg, unsigned e)
{
    asm volatile("s_waitcnt vmcnt(0)" ::: "memory");  // h write-through stores acked
    unsigned* sub  = bar + (wg >> 5) * 32;            // 8 counters, 128 B apart
    unsigned* root = bar + 256;
    unsigned* go   = bar + 288;
    __atomic_signal_fence(__ATOMIC_SEQ_CST);
    if (__hip_atomic_fetch_add(sub, 1u, __ATOMIC_RELAXED, __HIP_MEMORY_SCOPE_AGENT) == e * 32u - 1u)
        if (__hip_atomic_fetch_add(root, 1u, __ATOMIC_RELAXED, __HIP_MEMORY_SCOPE_AGENT) == e * 8u - 1u)
            __hip_atomic_store(go, e, __ATOMIC_RELAXED, __HIP_MEMORY_SCOPE_AGENT);
    while (__hip_atomic_load(go, __ATOMIC_RELAXED, __HIP_MEMORY_SCOPE_AGENT) < e)
        __builtin_amdgcn_s_sleep(1);
    __builtin_amdgcn_fence(__ATOMIC_ACQUIRE, "agent");  // buffer_inv sc1: L1+L2
}

// Plain-load GEMM (read-only A: pre-converted x). C[MT*16 x 16] += A * W^T segment.
template <int NC, int MT>
__device__ __forceinline__ void gemm_seg(const short* __restrict__ A, int lda,
                                         const short* __restrict__ W, int ldw,
                                         int kbase, int mbase, int col, int kq, float4v* acc)
{
#pragma unroll
    for (int kc = 0; kc < NC; ++kc) {
        const int k = kbase + kc * 32 + kq * 8;
        const short8 b = *(const short8*)(W + col * ldw + k);
#pragma unroll
        for (int mt = 0; mt < MT; ++mt) {
            const short8 a = *(const short8*)(A + (size_t)(mbase + mt * 16 + col) * lda + k);
            acc[mt] = __builtin_amdgcn_mfma_f32_16x16x32_bf16(a, b, acc[mt], 0, 0, 0);
        }
    }
}

// fp32-A fallback (x not pre-converted).
template <int NC, int MT>
__device__ __forceinline__ void gemm_seg_f32(const float* __restrict__ A, int lda,
                                             const short* __restrict__ W, int ldw,
                                             int kbase, int mbase, int col, int kq, float4v* acc)
{
#pragma unroll
    for (int kc = 0; kc < NC; ++kc) {
        const int k = kbase + kc * 32 + kq * 8;
        const short8 b = *(const short8*)(W + col * ldw + k);
#pragma unroll
        for (int mt = 0; mt < MT; ++mt) {
            const float* ap = A + (size_t)(mbase + mt * 16 + col) * lda + k;
            const float4v a0 = *(const float4v*)ap;
            const float4v a1 = *(const float4v*)(ap + 4);
            short8 a;
            a[0] = f2bf(a0[0]); a[1] = f2bf(a0[1]); a[2] = f2bf(a0[2]); a[3] = f2bf(a0[3]);
            a[4] = f2bf(a1[0]); a[5] = f2bf(a1[1]); a[6] = f2bf(a1[2]); a[7] = f2bf(a1[3]);
            acc[mt] = __builtin_amdgcn_mfma_f32_16x16x32_bf16(a, b, acc[mt], 0, 0, 0);
        }
    }
}

// Cached-A GEMM, single W.  (A freshness guaranteed by the per-step acquire fence.)
template <int NC, int MT>
__device__ __forceinline__ void gemm_br1(const short* A, int lda,
                                         const short* __restrict__ W, int ldw,
                                         int kbase, int mbase, int col, int kq, float4v* acc)
{
#pragma unroll
    for (int kc = 0; kc < NC; ++kc) {
        const int k = kbase + kc * 32 + kq * 8;
        const short8 b = *(const short8*)(W + col * ldw + k);
#pragma unroll
        for (int mt = 0; mt < MT; ++mt) {
            const short8 a = *(const short8*)(A + (size_t)(mbase + mt * 16 + col) * lda + k);
            acc[mt] = __builtin_amdgcn_mfma_f32_16x16x32_bf16(a, b, acc[mt], 0, 0, 0);
        }
    }
}

// Cached-A GEMM, FUSED two W (one A read feeds both accumulators).
template <int NC, int MT>
__device__ __forceinline__ void gemm_br2(const short* A, int lda,
                                         const short* __restrict__ W0,
                                         const short* __restrict__ W1, int ldw,
                                         int kbase, int mbase, int col, int kq,
                                         float4v* acc0, float4v* acc1)
{
#pragma unroll
    for (int kc = 0; kc < NC; ++kc) {
        const int k = kbase + kc * 32 + kq * 8;
        const short8 b0 = *(const short8*)(W0 + col * ldw + k);
        const short8 b1 = *(const short8*)(W1 + col * ldw + k);
#pragma unroll
        for (int mt = 0; mt < MT; ++mt) {
            const short8 a = *(const short8*)(A + (size_t)(mbase + mt * 16 + col) * lda + k);
            acc0[mt] = __builtin_amdgcn_mfma_f32_16x16x32_bf16(a, b0, acc0[mt], 0, 0, 0);
            acc1[mt] = __builtin_amdgcn_mfma_f32_16x16x32_bf16(a, b1, acc1[mt], 0, 0, 0);
        }
    }
}

// Fully fused steady-state step: two cached A streams, three weights.
template <int NC, int MT>
__device__ __forceinline__ void gemm_fused(const short* A0, const short* A1, int lda,
                                           const short* __restrict__ W0,
                                           const short* __restrict__ W1,
                                           const short* __restrict__ W2, int ldw,
                                           int kbase, int mbase, int col, int kq,
                                           float4v* acc0, float4v* acc1)
{
#pragma unroll
    for (int kc = 0; kc < NC; ++kc) {
        const int k = kbase + kc * 32 + kq * 8;
        short8 a0[MT], a1[MT];
#pragma unroll
        for (int mt = 0; mt < MT; ++mt) {
            a0[mt] = *(const short8*)(A0 + (size_t)(mbase + mt * 16 + col) * lda + k);
            a1[mt] = *(const short8*)(A1 + (size_t)(mbase + mt * 16 + col) * lda + k);
        }
        const short8 b0 = *(const short8*)(W0 + col * ldw + k);
        const short8 b1 = *(const short8*)(W1 + col * ldw + k);
        const short8 b2 = *(const short8*)(W2 + col * ldw + k);
#pragma unroll
        for (int mt = 0; mt < MT; ++mt) {
            acc0[mt] = __builtin_amdgcn_mfma_f32_16x16x32_bf16(a0[mt], b0, acc0[mt], 0, 0, 0);
            acc1[mt] = __builtin_amdgcn_mfma_f32_16x16x32_bf16(a0[mt], b1, acc1[mt], 0, 0, 0);
            acc1[mt] = __builtin_amdgcn_mfma_f32_16x16x32_bf16(a1[mt], b2, acc1[mt], 0, 0, 0);
        }
    }
}

__global__ void __launch_bounds__(NTHR, 1)
lstm_persistent(const float* __restrict__ xf,
                const float* __restrict__ Wi0, const float* __restrict__ Wh0,
                const float* __restrict__ bi0, const float* __restrict__ bh0,
                const float* __restrict__ Wi1, const float* __restrict__ Wh1,
                const float* __restrict__ bi1, const float* __restrict__ bh1,
                const float* __restrict__ h0in, const float* __restrict__ c0in,
                float* __restrict__ out,
                unsigned* __restrict__ bar,
                short* __restrict__ h0b,   // ws: [2][BH] bf16 L0 h dbuf (coherent)
                short* __restrict__ h1b,   // ws: [2][BH] bf16 L1 h dbuf (coherent)
                short* __restrict__ xbf,   // ws: [NX] bf16 x
                int use_pre)
{
    __shared__ short w0x[16][520];
    __shared__ short w0h[16][1032];
    __shared__ short w1x[16][1032];
    __shared__ short w1h[16][1032];
    __shared__ float gbuf[8][64][17];        // 8 K-partials
    __shared__ float bias0[16], bias1[16];
    __shared__ float cl0[64][4], cl1[64][4];

    const int wg   = blockIdx.x;
    const int tid  = threadIdx.x;
    const int wave = tid >> 6;
    const int lane = tid & 63;
    const int col  = lane & 15;
    const int kq   = lane >> 4;
    const int mq   = wave >> 3;          // 0..1  M-half (rows mq*32 .. +32)
    const int kk   = wave & 7;           // 0..7  K-eighth
    const int mb   = mq * 32;
    const int khb  = kk * 128;           // hh-GEMM K base (K=1024 / 8)
    const int kxb  = kk * 64;            // x-GEMM  K base (K=512  / 8)
    const int u0   = wg << 2;
    const int b    = tid >> 2;           // only valid for tid < 256
    const int uu   = tid & 3;
    const int ug   = u0 + uu;
    const size_t ci = (size_t)b * HID + ug;

#define GROW(cc) ((size_t)((cc) >> 2) * HID + u0 + ((cc) & 3))
    for (int idx = tid; idx < 16 * 128; idx += NTHR) {
        const int cc = idx >> 7, ch = (idx & 127) << 2;
        const float4v v = *(const float4v*)(Wi0 + GROW(cc) * IN_DIM + ch);
        short4v s; s[0] = f2bf(v[0]); s[1] = f2bf(v[1]); s[2] = f2bf(v[2]); s[3] = f2bf(v[3]);
        *(short4v*)&w0x[cc][ch] = s;
    }
    for (int idx = tid; idx < 16 * 256; idx += NTHR) {
        const int cc = idx >> 8, ch = (idx & 255) << 2;
        const size_t off = GROW(cc) * HID + ch;
        {
            const float4v v = *(const float4v*)(Wh0 + off);
            short4v s; s[0] = f2bf(v[0]); s[1] = f2bf(v[1]); s[2] = f2bf(v[2]); s[3] = f2bf(v[3]);
            *(short4v*)&w0h[cc][ch] = s;
        }
        {
            const float4v v = *(const float4v*)(Wi1 + off);
            short4v s; s[0] = f2bf(v[0]); s[1] = f2bf(v[1]); s[2] = f2bf(v[2]); s[3] = f2bf(v[3]);
            *(short4v*)&w1x[cc][ch] = s;
        }
        {
            const float4v v = *(const float4v*)(Wh1 + off);
            short4v s; s[0] = f2bf(v[0]); s[1] = f2bf(v[1]); s[2] = f2bf(v[2]); s[3] = f2bf(v[3]);
            *(short4v*)&w1h[cc][ch] = s;
        }
    }
    if (tid < 16) {
        bias0[tid] = bi0[GROW(tid)] + bh0[GROW(tid)];
        bias1[tid] = bi1[GROW(tid)] + bh1[GROW(tid)];
    }
    if (tid < 256) {
        cl0[b][uu] = c0in[ci];
        cl1[b][uu] = c0in[BH + ci];
        h0b[BH + ci] = f2bf(h0in[ci]);        // plain; CG sync below publishes
        h1b[BH + ci] = f2bf(h0in[BH + ci]);
    }

    if (wg == 0) {
        for (int i = tid; i < 320; i += NTHR)
            __hip_atomic_store(bar + i, 0u, __ATOMIC_RELAXED, __HIP_MEMORY_SCOPE_AGENT);
    }
    if (use_pre) {
        const size_t gtid = (size_t)blockIdx.x * NTHR + tid;
        for (size_t i = gtid * 4; i < NX; i += (size_t)NWG * NTHR * 4) {
            const float4v v = *(const float4v*)(xf + i);
            short4v s; s[0] = f2bf(v[0]); s[1] = f2bf(v[1]); s[2] = f2bf(v[2]); s[3] = f2bf(v[3]);
            *(short4v*)(xbf + i) = s;
        }
    }

    cg::grid_group grid = cg::this_grid();   // bootstrap: full release-acquire once
    __threadfence();
    grid.sync();
    __builtin_amdgcn_fence(__ATOMIC_ACQUIRE, "agent");  // cold caches for plain h reads

    const float4v z = {0.f, 0.f, 0.f, 0.f};

    // Super-step s: layer 0 computes t=s, layer 1 computes t=s-1.
    for (int s = 0; s <= T_STEPS; ++s) {
        float4v accL0[2] = {z, z};
        float4v accL1[2] = {z, z};

        // x-GEMM has no h dependency: run it BEFORE the barrier to overlap
        // barrier skew / store drain with useful MFMA work.
        if (s < T_STEPS) {
            if (use_pre)
                gemm_seg<2, 2>(xbf + (size_t)s * BATCH * IN_DIM, IN_DIM,
                               &w0x[0][0], 520, kxb, mb, col, kq, accL0);
            else
                gemm_seg_f32<2, 2>(xf + (size_t)s * BATCH * IN_DIM, IN_DIM,
                                   &w0x[0][0], 520, kxb, mb, col, kq, accL0);
        }

        if (s > 0) {
            __syncthreads();
            if (tid == 0) grid_bar(bar, wg, (unsigned)s);
            __syncthreads();
        }
        const short* h0p = h0b + (size_t)((s + 1) & 1) * BH;  // h0(s-1), also L1's input
        const short* h1p = h1b + (size_t)(s & 1) * BH;        // h1(s-2)

        if (s == 0) {
            gemm_br2<4, 2>(h0p, HID, &w0h[0][0], &w1x[0][0], 1032,
                           khb, mb, col, kq, accL0, accL1);
        } else if (s < T_STEPS) {
            gemm_fused<4, 2>(h0p, h1p, HID, &w0h[0][0], &w1x[0][0], &w1h[0][0], 1032,
                             khb, mb, col, kq, accL0, accL1);
        } else {
            gemm_br1<4, 2>(h0p, HID, &w1x[0][0], 1032, khb, mb, col, kq, accL1);
            gemm_br1<4, 2>(h1p, HID, &w1h[0][0], 1032, khb, mb, col, kq, accL1);
        }

        if (s < T_STEPS) {  // ---- layer 0 reduce + elementwise ----
#pragma unroll
            for (int mt = 0; mt < 2; ++mt)
#pragma unroll
                for (int r = 0; r < 4; ++r)
                    gbuf[kk][mb + mt * 16 + kq * 4 + r][col] = accL0[mt][r];
            __syncthreads();
            if (tid < 256) {
                float g4[4];
#pragma unroll
                for (int gi_ = 0; gi_ < 4; ++gi_) {
                    float v = bias0[gi_ * 4 + uu];
#pragma unroll
                    for (int p = 0; p < 8; ++p) v += gbuf[p][b][gi_ * 4 + uu];
                    g4[gi_] = v;
                }
                const float cn = sigmoidf_(g4[1]) * cl0[b][uu] + sigmoidf_(g4[0]) * tanhf(g4[2]);
                const float hn = sigmoidf_(g4[3]) * tanhf(cn);
                cl0[b][uu] = cn;
                cohstore_h(h0b + (size_t)(s & 1) * BH + ci, f2bf(hn));
            }
            __syncthreads();  // gbuf reuse by layer 1
        }

        if (s >= 1) {  // ---- layer 1 reduce + elementwise (t = s-1) ----
            const int t = s - 1;
#pragma unroll
            for (int mt = 0; mt < 2; ++mt)
#pragma unroll
                for (int r = 0; r < 4; ++r)
                    gbuf[kk][mb + mt * 16 + kq * 4 + r][col] = accL1[mt][r];
            __syncthreads();
            if (tid < 256) {
                float g4[4];
#pragma unroll
                for (int gi_ = 0; gi_ < 4; ++gi_) {
                    float v = bias1[gi_ * 4 + uu];
#pragma unroll
                    for (int p = 0; p < 8; ++p) v += gbuf[p][b][gi_ * 4 + uu];
                    g4[gi_] = v;
                }
                const float cn = sigmoidf_(g4[1]) * cl1[b][uu] + sigmoidf_(g4[0]) * tanhf(g4[2]);
                const float hn = sigmoidf_(g4[3]) * tanhf(cn);
                cl1[b][uu] = cn;
                cohstore_h(h1b + (size_t)(t & 1) * BH + ci, f2bf(hn));
                out[(size_t)t * BH + ci] = hn;   // plain store, write-only stream
            }
            __syncthreads();
        }
    }

    if (tid < 256) {
        out[OPS_SZ + ci]                  = bf2f(cohload_h(h0b + (size_t)((T_STEPS - 1) & 1) * BH + ci));
        out[OPS_SZ + BH + ci]             = bf2f(cohload_h(h1b + (size_t)((T_STEPS - 1) & 1) * BH + ci));
        out[OPS_SZ + 2 * (size_t)BH + ci] = cl0[b][uu];
        out[OPS_SZ + 3 * (size_t)BH + ci] = cl1[b][uu];
    }
#undef GROW
}

extern "C" void kernel_launch(void* const* d_in, const int* in_sizes, int n_in,
                              void* d_out, int out_size, void* d_ws, size_t ws_size,
                              hipStream_t stream)
{
    const float* x    = (const float*)d_in[0];
    const float* h0   = (const float*)d_in[1];
    const float* c0   = (const float*)d_in[2];
    const float* Wi0  = (const float*)d_in[3];
    const float* Wh0  = (const float*)d_in[4];
    const float* bi0  = (const float*)d_in[5];
    const float* bh0  = (const float*)d_in[6];
    const float* Wi1  = (const float*)d_in[7];
    const float* Wh1  = (const float*)d_in[8];
    const float* bi1  = (const float*)d_in[9];
    const float* bh1  = (const float*)d_in[10];
    float* out = (float*)d_out;

    unsigned* bar = (unsigned*)d_ws;
    short* h0b = (short*)((char*)d_ws + BAR_BYTES);
    short* h1b = h0b + (size_t)2 * BH;
    short* xbf = h1b + (size_t)2 * BH;
    int use_pre = (ws_size >= BAR_BYTES + ((size_t)4 * BH + NX) * sizeof(short)) ? 1 : 0;

    void* args[] = {(void*)&x, (void*)&Wi0, (void*)&Wh0, (void*)&bi0, (void*)&bh0,
                    (void*)&Wi1, (void*)&Wh1, (void*)&bi1, (void*)&bh1,
                    (void*)&h0, (void*)&c0, (void*)&out,
                    (void*)&bar, (void*)&h0b, (void*)&h1b, (void*)&xbf, (void*)&use_pre};
    hipLaunchCooperativeKernel((void*)lstm_persistent, dim3(NWG), dim3(NTHR),
                               args, 0, stream);
}